// Round 18
// baseline (2213.369 us; speedup 1.0000x reference)
//
#include <hip/hip_runtime.h>
#include <hip/hip_bf16.h>
#include <math.h>

// ---------------- problem constants ----------------
#define B_   8
#define L_   24
#define LP_  48
#define N_   325
#define D_   128
#define H_   8
#define NL_  3
#define DFF_ 512

typedef __attribute__((ext_vector_type(8))) short s16x8;
typedef __attribute__((ext_vector_type(4))) float f32x4;
typedef __hip_bfloat16 bf16;

static const int  ROWS    = B_ * L_ * N_;        // 62400
static const int  T_SELF  = L_ * N_;             // 7800
static const int  T_CROSS = LP_ * N_;            // 15600
static const long long U_ = (long long)T_SELF * D_;   // 998,400
static const long long SZ = (long long)B_ * U_;       // 7,987,200

enum { EPI_NONE = 0, EPI_ELU1 = 1, EPI_GELU = 2 };

struct MOut { void* d[3]; int ldc_[3]; int flg[3]; };   // flg = epi (bf16 out implied)

__device__ __forceinline__ float apply_epi(float v, int epi) {
    if (epi == EPI_ELU1) return (v > 0.f) ? (v + 1.f) : expf(v);
    if (epi == EPI_GELU) return 0.5f * v * (1.f + erff(v * 0.70710678118654752f));
    return v;
}

// Bijective XCD-chunked swizzle (m204)
__device__ __forceinline__ int xcd_swz(int bid, int nwg) {
    int q = nwg >> 3, r = nwg & 7;
    int xcd = bid & 7, lid = bid >> 3;
    return (xcd < r ? xcd * (q + 1) : r * (q + 1) + (xcd - r) * q) + lid;
}

// =====================================================================
// 64x64-tile MFMA GEMM (18.4KB LDS -> 8 blocks/CU). K % 64 == 0.
// 1D grid.x = MB*NB, decoded n-fast after XCD swizzle.
// =====================================================================
template<int ABF>
__global__ __launch_bounds__(256) void gk64(
    const void* __restrict__ Av, const bf16* __restrict__ Bt,
    const float* __restrict__ bias, void* __restrict__ Cv,
    int M, int Nc, int K,
    long long sA, long long sB, long long sC,
    int lda, int ldb, int ldc,
    int bmod, long long sBias, int accum, int epi, int obf, int rowbias, int npad)
{
    const int batch = blockIdx.z;
    const int NB = (npad + 63) >> 6;
    const int wgid = xcd_swz(blockIdx.x, gridDim.x);
    const int m0 = (wgid / NB) * 64, n0 = (wgid % NB) * 64;
    const int tid = threadIdx.x, lane = tid & 63;
    const int w = tid >> 6, wm = w >> 1, wn = w & 1;
    const int r16 = lane & 15, kb = lane >> 4;

    __shared__ __align__(16) bf16 shm[64 * 144];

    const float* Af = ABF ? nullptr : ((const float*)Av + (long long)batch * sA);
    const bf16*  Ab = ABF ? ((const bf16*)Av + (long long)batch * sA) : nullptr;
    const bf16*  Bp = Bt + (long long)(batch % bmod) * sB;

    f32x4 acc[2][2];
#pragma unroll
    for (int i = 0; i < 2; ++i)
#pragma unroll
        for (int j = 0; j < 2; ++j) acc[i][j] = f32x4{0.f, 0.f, 0.f, 0.f};

    for (int k0 = 0; k0 < K; k0 += 64) {
#pragma unroll
        for (int s = 0; s < 2; ++s) {
            int slot = tid + s * 256;
            int row = slot >> 3, kg = slot & 7;
            int m = m0 + row, k = k0 + kg * 8;
            union { s16x8 v; bf16 h[8]; } val;
            if (m < M) {
                if (ABF) {
                    val.v = *(const s16x8*)(Ab + (long long)m * lda + k);
                } else {
                    f32x4 v0 = *(const f32x4*)(Af + (long long)m * lda + k);
                    f32x4 v1 = *(const f32x4*)(Af + (long long)m * lda + k + 4);
#pragma unroll
                    for (int e = 0; e < 4; ++e) {
                        val.h[e]     = __float2bfloat16(v0[e]);
                        val.h[e + 4] = __float2bfloat16(v1[e]);
                    }
                }
            } else {
#pragma unroll
                for (int e = 0; e < 8; ++e) val.h[e] = __float2bfloat16(0.f);
            }
            *(s16x8*)&shm[row * 72 + kg * 8] = val.v;
        }
#pragma unroll
        for (int s = 0; s < 2; ++s) {
            int slot = tid + s * 256;
            int row = slot >> 3, kg = slot & 7;
            int n = n0 + row, k = k0 + kg * 8;
            union { s16x8 v; bf16 h[8]; } val;
            if (n < Nc) {
                val.v = *(const s16x8*)(Bp + (long long)n * ldb + k);
            } else {
#pragma unroll
                for (int e = 0; e < 8; ++e) val.h[e] = __float2bfloat16(0.f);
            }
            *(s16x8*)&shm[4608 + row * 72 + kg * 8] = val.v;
        }
        __syncthreads();
#pragma unroll
        for (int kh = 0; kh < 2; ++kh) {
            s16x8 av[2], bv[2];
#pragma unroll
            for (int mi = 0; mi < 2; ++mi)
                av[mi] = *(const s16x8*)&shm[(wm * 32 + mi * 16 + r16) * 72 + kh * 32 + kb * 8];
#pragma unroll
            for (int ni = 0; ni < 2; ++ni)
                bv[ni] = *(const s16x8*)&shm[4608 + (wn * 32 + ni * 16 + r16) * 72 + kh * 32 + kb * 8];
#pragma unroll
            for (int mi = 0; mi < 2; ++mi)
#pragma unroll
                for (int ni = 0; ni < 2; ++ni)
                    acc[mi][ni] = __builtin_amdgcn_mfma_f32_16x16x32_bf16(
                        av[mi], bv[ni], acc[mi][ni], 0, 0, 0);
        }
        __syncthreads();
    }

    const float* bp = bias ? (bias + (long long)(batch % bmod) * sBias) : nullptr;
    if (obf) {
        bf16* Cb = (bf16*)Cv + (long long)batch * sC;
#pragma unroll
        for (int mi = 0; mi < 2; ++mi)
#pragma unroll
            for (int ni = 0; ni < 2; ++ni)
#pragma unroll
                for (int rr = 0; rr < 4; ++rr) {
                    int row = wm * 32 + mi * 16 + kb * 4 + rr;
                    int col = wn * 32 + ni * 16 + r16;
                    int m = m0 + row, n = n0 + col;
                    float v = 0.f;
                    if (m < M && n < Nc) {
                        v = acc[mi][ni][rr];
                        if (bp) v += rowbias ? bp[m] : bp[n];
                        v = apply_epi(v, epi);
                    }
                    shm[row * 72 + col] = __float2bfloat16(v);
                }
        __syncthreads();
#pragma unroll
        for (int it = 0; it < 2; ++it) {
            int row = (tid >> 3) + it * 32;
            int col = (tid & 7) * 8;
            int m = m0 + row, nglob = n0 + col;
            if (m < M && nglob < npad)
                *(s16x8*)(Cb + (long long)m * ldc + nglob) = *(const s16x8*)&shm[row * 72 + col];
        }
        return;
    }

    float* Cf = (float*)Cv + (long long)batch * sC;
#pragma unroll
    for (int mi = 0; mi < 2; ++mi) {
#pragma unroll
        for (int ni = 0; ni < 2; ++ni) {
#pragma unroll
            for (int rr = 0; rr < 4; ++rr) {
                int m = m0 + wm * 32 + mi * 16 + kb * 4 + rr;
                int n = n0 + wn * 32 + ni * 16 + r16;
                if (m >= M || n >= Nc) continue;
                float v = acc[mi][ni][rr];
                if (bp) v += rowbias ? bp[m] : bp[n];
                v = apply_epi(v, epi);
                long long ci = (long long)m * ldc + n;
                if (accum) Cf[ci] += v; else Cf[ci] = v;
            }
        }
    }
}

// =====================================================================
// 64x64 MULTI GEMM (z==1, Nc = 128*NOUT), XCD-swizzled 1D grid.
// =====================================================================
template<int ABF>
__global__ __launch_bounds__(256) void gk64m(
    const void* __restrict__ Av, const bf16* __restrict__ Bt,
    const float* __restrict__ bias, MOut mo, int M, int K, int lda, int ldb, int NB)
{
    const int wgid = xcd_swz(blockIdx.x, gridDim.x);
    const int bn = wgid % NB;
    const int m0 = (wgid / NB) * 64, n0 = bn * 64;
    const int tid = threadIdx.x, lane = tid & 63;
    const int w = tid >> 6, wm = w >> 1, wn = w & 1;
    const int r16 = lane & 15, kb = lane >> 4;

    __shared__ __align__(16) bf16 shm[64 * 144];

    const float* Af = ABF ? nullptr : (const float*)Av;
    const bf16*  Ab = ABF ? (const bf16*)Av : nullptr;

    f32x4 acc[2][2];
#pragma unroll
    for (int i = 0; i < 2; ++i)
#pragma unroll
        for (int j = 0; j < 2; ++j) acc[i][j] = f32x4{0.f, 0.f, 0.f, 0.f};

    for (int k0 = 0; k0 < K; k0 += 64) {
#pragma unroll
        for (int s = 0; s < 2; ++s) {
            int slot = tid + s * 256;
            int row = slot >> 3, kg = slot & 7;
            int m = m0 + row, k = k0 + kg * 8;
            union { s16x8 v; bf16 h[8]; } val;
            if (m < M) {
                if (ABF) {
                    val.v = *(const s16x8*)(Ab + (long long)m * lda + k);
                } else {
                    f32x4 v0 = *(const f32x4*)(Af + (long long)m * lda + k);
                    f32x4 v1 = *(const f32x4*)(Af + (long long)m * lda + k + 4);
#pragma unroll
                    for (int e = 0; e < 4; ++e) {
                        val.h[e]     = __float2bfloat16(v0[e]);
                        val.h[e + 4] = __float2bfloat16(v1[e]);
                    }
                }
            } else {
#pragma unroll
                for (int e = 0; e < 8; ++e) val.h[e] = __float2bfloat16(0.f);
            }
            *(s16x8*)&shm[row * 72 + kg * 8] = val.v;
        }
#pragma unroll
        for (int s = 0; s < 2; ++s) {
            int slot = tid + s * 256;
            int row = slot >> 3, kg = slot & 7;
            int n = n0 + row, k = k0 + kg * 8;
            *(s16x8*)&shm[4608 + row * 72 + kg * 8] =
                *(const s16x8*)(Bt + (long long)n * ldb + k);
        }
        __syncthreads();
#pragma unroll
        for (int kh = 0; kh < 2; ++kh) {
            s16x8 av[2], bv[2];
#pragma unroll
            for (int mi = 0; mi < 2; ++mi)
                av[mi] = *(const s16x8*)&shm[(wm * 32 + mi * 16 + r16) * 72 + kh * 32 + kb * 8];
#pragma unroll
            for (int ni = 0; ni < 2; ++ni)
                bv[ni] = *(const s16x8*)&shm[4608 + (wn * 32 + ni * 16 + r16) * 72 + kh * 32 + kb * 8];
#pragma unroll
            for (int mi = 0; mi < 2; ++mi)
#pragma unroll
                for (int ni = 0; ni < 2; ++ni)
                    acc[mi][ni] = __builtin_amdgcn_mfma_f32_16x16x32_bf16(
                        av[mi], bv[ni], acc[mi][ni], 0, 0, 0);
        }
        __syncthreads();
    }

    const int oi = bn >> 1;
    const int epi_ = mo.flg[oi];
    bf16* Cb = (bf16*)mo.d[oi];
    const int ldcc = mo.ldc_[oi];
    const int cbase = (bn & 1) * 64;
#pragma unroll
    for (int mi = 0; mi < 2; ++mi)
#pragma unroll
        for (int ni = 0; ni < 2; ++ni)
#pragma unroll
            for (int rr = 0; rr < 4; ++rr) {
                int row = wm * 32 + mi * 16 + kb * 4 + rr;
                int col = wn * 32 + ni * 16 + r16;
                int m = m0 + row;
                float v = 0.f;
                if (m < M) {
                    v = acc[mi][ni][rr] + bias[n0 + col];
                    v = apply_epi(v, epi_);
                }
                shm[row * 72 + col] = __float2bfloat16(v);
            }
    __syncthreads();
#pragma unroll
    for (int it = 0; it < 2; ++it) {
        int row = (tid >> 3) + it * 32;
        int col = (tid & 7) * 8;
        int m = m0 + row;
        if (m < M)
            *(s16x8*)(Cb + (long long)m * ldcc + cbase + col) = *(const s16x8*)&shm[row * 72 + col];
    }
}

// =====================================================================
// gkLN: 64x128 full-row GEMM + fused residual+LayerNorm epilogue.
// Residual + bias loads are HOISTED before the K-loop (latency hidden).
// ATTN: A-operand is raw elu'd Q-projection; the linear-attention combine
//   is computed during A staging with vectorized f32x4 kv/ksum loads.
// WRAW: also store raw (A@Bt + bias) to rawC. RBF: resid dtype.
// =====================================================================
template<int RBF, int WRAW, int ATTN>
__global__ __launch_bounds__(256) void gkLN(
    const bf16* __restrict__ Ab, const bf16* __restrict__ Bt,
    const float* __restrict__ bias, bf16* __restrict__ rawC,
    const void* __restrict__ resid, const float* __restrict__ g,
    const float* __restrict__ beta, bf16* __restrict__ outp,
    const float* __restrict__ kvt, const float* __restrict__ kst,
    int M, int K, int lda, int ldb)
{
    const int m0 = blockIdx.x * 64;
    const int tid = threadIdx.x, lane = tid & 63;
    const int w = tid >> 6, wm = w >> 1, wn = w & 1;
    const int r16 = lane & 15, kb = lane >> 4;

    __shared__ __align__(16) bf16 shm[64 * 72 + 128 * 72];  // A | B; epi reuse [64][136]
    __shared__ float red[2][2][64];

    // ---- hoisted residual + bias loads (latency hides under K-loop) ----
    float rres[2][4][4];
    float rbias[4];
#pragma unroll
    for (int ni = 0; ni < 4; ++ni)
        rbias[ni] = bias[wn * 64 + ni * 16 + r16];
#pragma unroll
    for (int mi = 0; mi < 2; ++mi)
#pragma unroll
        for (int rr = 0; rr < 4; ++rr) {
            const int row = wm * 32 + mi * 16 + kb * 4 + rr;
            const int m = m0 + row;
#pragma unroll
            for (int ni = 0; ni < 4; ++ni) {
                const int col = wn * 64 + ni * 16 + r16;
                rres[mi][ni][rr] = (m < M)
                    ? (RBF ? __bfloat162float(((const bf16*)resid)[(long long)m * 128 + col])
                           : ((const float*)resid)[(long long)m * 128 + col])
                    : 0.f;
            }
        }

    f32x4 acc[2][4];
#pragma unroll
    for (int i = 0; i < 2; ++i)
#pragma unroll
        for (int j = 0; j < 4; ++j) acc[i][j] = f32x4{0.f, 0.f, 0.f, 0.f};

    for (int k0 = 0; k0 < K; k0 += 64) {
#pragma unroll
        for (int s = 0; s < 2; ++s) {                  // A[64][64]
            int slot = tid + s * 256;
            int row = slot >> 3, kg = slot & 7;
            int m = m0 + row, k = k0 + kg * 8;
            union { s16x8 v; bf16 h[8]; } val;
            if (m < M) {
                if (ATTN) {
                    const int h = k >> 4, d0 = k & 8;
                    const int b = m / T_SELF;
                    const bf16* qrow = Ab + (long long)m * 128 + h * 16;
                    const float* ksp = kst + ((b << 3) + h) * 16;
                    const float* kvp = kvt + ((long long)((b << 3) + h) << 8) + d0;
                    union { s16x8 v; bf16 h8[8]; } q0, q1;
                    q0.v = *(const s16x8*)(qrow);
                    q1.v = *(const s16x8*)(qrow + 8);
                    float q[16];
#pragma unroll
                    for (int e = 0; e < 8; ++e) {
                        q[e]     = __bfloat162float(q0.h8[e]);
                        q[e + 8] = __bfloat162float(q1.h8[e]);
                    }
                    float den = 1e-6f;
#pragma unroll
                    for (int e4 = 0; e4 < 4; ++e4) {
                        f32x4 ks4 = *(const f32x4*)(ksp + e4 * 4);
#pragma unroll
                        for (int t = 0; t < 4; ++t)
                            den = fmaf(q[e4 * 4 + t], ks4[t], den);
                    }
                    const float rd = 1.f / den;
                    float o[8];
#pragma unroll
                    for (int j = 0; j < 8; ++j) o[j] = 0.f;
#pragma unroll
                    for (int e = 0; e < 16; ++e) {
                        f32x4 a = *(const f32x4*)(kvp + e * 16);
                        f32x4 bb = *(const f32x4*)(kvp + e * 16 + 4);
#pragma unroll
                        for (int t = 0; t < 4; ++t) {
                            o[t]     = fmaf(q[e], a[t],  o[t]);
                            o[t + 4] = fmaf(q[e], bb[t], o[t + 4]);
                        }
                    }
#pragma unroll
                    for (int j = 0; j < 8; ++j)
                        val.h[j] = __float2bfloat16(o[j] * rd);
                } else {
                    val.v = *(const s16x8*)(Ab + (long long)m * lda + k);
                }
            } else {
#pragma unroll
                for (int e = 0; e < 8; ++e) val.h[e] = __float2bfloat16(0.f);
            }
            *(s16x8*)&shm[row * 72 + kg * 8] = val.v;
        }
#pragma unroll
        for (int s = 0; s < 4; ++s) {                  // B[128][64]
            int slot = tid + s * 256;
            int row = slot >> 3, kg = slot & 7;
            *(s16x8*)&shm[4608 + row * 72 + kg * 8] =
                *(const s16x8*)(Bt + (long long)row * ldb + k0 + kg * 8);
        }
        __syncthreads();
#pragma unroll
        for (int kh = 0; kh < 2; ++kh) {
            s16x8 av[2], bv[4];
#pragma unroll
            for (int mi = 0; mi < 2; ++mi)
                av[mi] = *(const s16x8*)&shm[(wm * 32 + mi * 16 + r16) * 72 + kh * 32 + kb * 8];
#pragma unroll
            for (int ni = 0; ni < 4; ++ni)
                bv[ni] = *(const s16x8*)&shm[4608 + (wn * 64 + ni * 16 + r16) * 72 + kh * 32 + kb * 8];
#pragma unroll
            for (int mi = 0; mi < 2; ++mi)
#pragma unroll
                for (int ni = 0; ni < 4; ++ni)
                    acc[mi][ni] = __builtin_amdgcn_mfma_f32_16x16x32_bf16(
                        av[mi], bv[ni], acc[mi][ni], 0, 0, 0);
        }
        __syncthreads();
    }

    // ---- epilogue: v = acc + bias; (raw write); t = v + resid; LN ----
    float psum[8], psq[8];
#pragma unroll
    for (int t = 0; t < 8; ++t) { psum[t] = 0.f; psq[t] = 0.f; }

#pragma unroll
    for (int mi = 0; mi < 2; ++mi)
#pragma unroll
        for (int rr = 0; rr < 4; ++rr) {
            const int row = wm * 32 + mi * 16 + kb * 4 + rr;
#pragma unroll
            for (int ni = 0; ni < 4; ++ni) {
                const int col = wn * 64 + ni * 16 + r16;
                float v = acc[mi][ni][rr] + rbias[ni];
                if (WRAW) shm[row * 136 + col] = __float2bfloat16(v);
                float t = v + rres[mi][ni][rr];
                acc[mi][ni][rr] = t;
                psum[mi * 4 + rr] += t;
                psq[mi * 4 + rr]  += t * t;
            }
        }

    if (WRAW) {
        __syncthreads();
#pragma unroll
        for (int it = 0; it < 4; ++it) {
            int id = tid + it * 256;
            int row = id >> 4, colc = (id & 15) * 8;
            int m = m0 + row;
            if (m < M)
                *(s16x8*)(rawC + (long long)m * 128 + colc) = *(const s16x8*)&shm[row * 136 + colc];
        }
    }

#pragma unroll
    for (int off = 1; off < 16; off <<= 1) {
#pragma unroll
        for (int t = 0; t < 8; ++t) {
            psum[t] += __shfl_xor(psum[t], off);
            psq[t]  += __shfl_xor(psq[t], off);
        }
    }
    __syncthreads();
    if (r16 == 0) {
#pragma unroll
        for (int mi = 0; mi < 2; ++mi)
#pragma unroll
            for (int rr = 0; rr < 4; ++rr) {
                const int row = wm * 32 + mi * 16 + kb * 4 + rr;
                red[wn][0][row] = psum[mi * 4 + rr];
                red[wn][1][row] = psq[mi * 4 + rr];
            }
    }
    __syncthreads();

#pragma unroll
    for (int mi = 0; mi < 2; ++mi)
#pragma unroll
        for (int rr = 0; rr < 4; ++rr) {
            const int row = wm * 32 + mi * 16 + kb * 4 + rr;
            const float mean = (red[0][0][row] + red[1][0][row]) * (1.f / 128.f);
            const float msq  = (red[0][1][row] + red[1][1][row]) * (1.f / 128.f);
            const float rstd = rsqrtf(msq - mean * mean + 1e-5f);
#pragma unroll
            for (int ni = 0; ni < 4; ++ni) {
                const int col = wn * 64 + ni * 16 + r16;
                shm[row * 136 + col] = __float2bfloat16(
                    (acc[mi][ni][rr] - mean) * rstd * g[col] + beta[col]);
            }
        }
    __syncthreads();
#pragma unroll
    for (int it = 0; it < 4; ++it) {
        int id = tid + it * 256;
        int row = id >> 4, colc = (id & 15) * 8;
        int m = m0 + row;
        if (m < M)
            *(s16x8*)(outp + (long long)m * 128 + colc) = *(const s16x8*)&shm[row * 136 + colc];
    }
}

static inline void gemm64(hipStream_t st, int abf, const void* A, const bf16* Bt,
                          const float* bias, void* C,
                          int M, int Nc, int K,
                          long long sA, long long sB, long long sC,
                          int lda, int ldb, int ldc,
                          int z, int bmod, long long sBias, int accum, int epi, int obf,
                          int rowbias = 0, int npad = 0)
{
    if (npad < Nc) npad = Nc;
    dim3 g(((npad + 63) / 64) * ((M + 63) / 64), 1, z);
    if (abf) gk64<1><<<g,256,0,st>>>(A,Bt,bias,C,M,Nc,K,sA,sB,sC,lda,ldb,ldc,bmod,sBias,accum,epi,obf,rowbias,npad);
    else     gk64<0><<<g,256,0,st>>>(A,Bt,bias,C,M,Nc,K,sA,sB,sC,lda,ldb,ldc,bmod,sBias,accum,epi,obf,rowbias,npad);
}

static inline void gemm3_64(hipStream_t st, int abf, const void* A, const bf16* Bt,
                            const float* bias, const MOut& mo, int M, int Nc, int K,
                            int lda, int ldb)
{
    const int NB = Nc / 64;
    dim3 g(NB * ((M + 63) / 64), 1, 1);
    if (abf) gk64m<1><<<g,256,0,st>>>(A,Bt,bias,mo,M,K,lda,ldb,NB);
    else     gk64m<0><<<g,256,0,st>>>(A,Bt,bias,mo,M,K,lda,ldb,NB);
}

static inline void gemmLN(hipStream_t st, int rbf, int wraw, int attn,
                          const bf16* A, const bf16* Bt, const float* bias, bf16* rawC,
                          const void* resid, const float* g, const float* beta, bf16* outp,
                          const float* kvt, const float* kst,
                          int M, int K, int lda, int ldb)
{
    dim3 gr((M + 63) / 64);
    if (attn) {
        if (rbf) gkLN<1,0,1><<<gr,256,0,st>>>(A,Bt,bias,rawC,resid,g,beta,outp,kvt,kst,M,K,lda,ldb);
        else     gkLN<0,0,1><<<gr,256,0,st>>>(A,Bt,bias,rawC,resid,g,beta,outp,kvt,kst,M,K,lda,ldb);
    } else if (rbf) {
        if (wraw) gkLN<1,1,0><<<gr,256,0,st>>>(A,Bt,bias,rawC,resid,g,beta,outp,kvt,kst,M,K,lda,ldb);
        else      gkLN<1,0,0><<<gr,256,0,st>>>(A,Bt,bias,rawC,resid,g,beta,outp,kvt,kst,M,K,lda,ldb);
    } else {
        if (wraw) gkLN<0,1,0><<<gr,256,0,st>>>(A,Bt,bias,rawC,resid,g,beta,outp,kvt,kst,M,K,lda,ldb);
        else      gkLN<0,0,0><<<gr,256,0,st>>>(A,Bt,bias,rawC,resid,g,beta,outp,kvt,kst,M,K,lda,ldb);
    }
}

// =====================================================================
// transpose-convert
// =====================================================================
template<int SBF>
__global__ __launch_bounds__(256) void tconv(
    const void* __restrict__ srcv, bf16* __restrict__ dst,
    int R, int C, int lds_, long long sS, int rbound, int drs, long long sD)
{
    const int bz = blockIdx.z;
    const float* sf = SBF ? nullptr : ((const float*)srcv + (long long)bz * sS);
    const bf16* sb = SBF ? ((const bf16*)srcv + (long long)bz * sS) : nullptr;
    bf16* dp = dst + (long long)bz * sD;
    __shared__ float t[32][33];
    const int r0 = blockIdx.x * 32, c0 = blockIdx.y * 32;
    for (int i = threadIdx.y; i < 32; i += 8) {
        int r = r0 + i, c = c0 + threadIdx.x;
        float v = 0.f;
        if (r < R && c < C)
            v = SBF ? __bfloat162float(sb[(long long)r * lds_ + c]) : sf[(long long)r * lds_ + c];
        t[i][threadIdx.x] = v;
    }
    __syncthreads();
    for (int i = threadIdx.y; i < 32; i += 8) {
        int c = c0 + i, r = r0 + threadIdx.x;
        if (c < C && r < rbound) dp[(long long)c * drs + r] = __float2bfloat16(t[threadIdx.x][i]);
    }
}

// strided f32 -> bf16 convert
__global__ __launch_bounds__(256) void conv_k(
    const float* __restrict__ src, bf16* __restrict__ dst,
    long long total, int C, int slds, int dldd)
{
    for (long long idx = blockIdx.x * 256LL + threadIdx.x; idx < total;
         idx += (long long)gridDim.x * 256) {
        long long r = idx / C; int c = (int)(idx - r * C);
        dst[r * dldd + c] = __float2bfloat16(src[r * slds + c]);
    }
}

// GSUM[j] = sum_i GSKT[i][j]
__global__ __launch_bounds__(256) void gsum_k(
    const bf16* __restrict__ gskt, bf16* __restrict__ gsum, long long per)
{
    for (long long j = blockIdx.x * 256LL + threadIdx.x; j < per;
         j += (long long)gridDim.x * 256) {
        float a = __bfloat162float(gskt[j]) + __bfloat162float(gskt[per + j])
                + __bfloat162float(gskt[2 * per + j]);
        gsum[j] = __float2bfloat16(a);
    }
}

// BSK[l][o] = sum_i ( skb[i][o] + sum_c gcnb[i*24+l][c] * skW[i][c][o] )
__global__ __launch_bounds__(128) void bsk_k(
    const float* __restrict__ gcnb, const float* __restrict__ skW,
    const float* __restrict__ skb, float* __restrict__ out)
{
    const int l = blockIdx.x, o = threadIdx.x;
    float acc = 0.f;
    for (int i = 0; i < NL_; ++i) {
        acc += skb[i * 128 + o];
        const float* gb = gcnb + (i * 24 + l) * 128;
        const float* sw = skW + i * 16384;
        for (int c = 0; c < 128; ++c) acc += gb[c] * sw[c * 128 + o];
    }
    out[l * 128 + o] = acc;
}

__global__ __launch_bounds__(384) void cbias_k(
    const float* __restrict__ bq, const float* __restrict__ bk,
    const float* __restrict__ bv, float* __restrict__ bqkv)
{
    const int wi = blockIdx.x, j = threadIdx.x;
    float v = (j < 128) ? bq[wi * 128 + j] : (j < 256) ? bk[wi * 128 + j - 128] : bv[wi * 128 + j - 256];
    bqkv[wi * 384 + j] = v;
}

// ---------------- linear attention partial kv ----------------
__global__ __launch_bounds__(256) void kv_part_bf16(
    const bf16* __restrict__ kp, const bf16* __restrict__ vp,
    float* __restrict__ part, int T, int TC)
{
    const int z = blockIdx.z, h = blockIdx.y, tc = blockIdx.x;
    kp += (long long)z * T * D_;
    vp += (long long)z * T * D_;
    const int t0 = tc * 512;
    const int tend = min(T, t0 + 512);
    const int tid = threadIdx.x;
    const int e = tid >> 4, d = tid & 15;
    __shared__ float sk[64][16];
    __shared__ float sv[64][16];
    float acc = 0.f, asum = 0.f;
    for (int tb = t0; tb < tend; tb += 64) {
#pragma unroll
        for (int r = 0; r < 4; ++r) {
            int idx = tid + r * 256, tt = idx >> 4, c = idx & 15;
            int t = tb + tt;
            float kk = 0.f, vv = 0.f;
            if (t < tend) {
                long long gi = (long long)t * D_ + h * 16 + c;
                kk = __bfloat162float(kp[gi]);
                vv = __bfloat162float(vp[gi]);
            }
            sk[tt][c] = kk; sv[tt][c] = vv;
        }
        __syncthreads();
#pragma unroll 8
        for (int tt = 0; tt < 64; ++tt) {
            float ke = sk[tt][e];
            acc  = fmaf(ke, sv[tt][d], acc);
            asum += ke;
        }
        __syncthreads();
    }
    float* pp = part + (((long long)z * TC + tc) * H_ + h) * 272;
    pp[e * 16 + d] = acc;
    if (d == 0) pp[256 + e] = asum;
}

__global__ __launch_bounds__(256) void kv_reduce2(
    const float* __restrict__ part, float* __restrict__ kv,
    float* __restrict__ ksum, int b0, int TC)
{
    const int h = blockIdx.x, z = blockIdx.y, b = b0 + z;
    const float* pz = part + (long long)z * TC * H_ * 272;
    const int tid = threadIdx.x, e = tid >> 4, d = tid & 15;
    float acc = 0.f;
    for (int tc = 0; tc < TC; ++tc) acc += pz[((long long)tc * H_ + h) * 272 + e * 16 + d];
    kv[((long long)(b * H_ + h) * 16 + e) * 16 + d] = acc;
    if (d == 0) {
        float s = 0.f;
        for (int tc = 0; tc < TC; ++tc) s += pz[((long long)tc * H_ + h) * 272 + 256 + e];
        ksum[(b * H_ + h) * 16 + e] = s;
    }
}

// ---------------- fused (residual|relu) + LayerNorm (final only) ----------------
template<int XBF, int OBF>
__global__ __launch_bounds__(256) void addln_k(
    const void* __restrict__ xin, const bf16* __restrict__ addend,
    const float* __restrict__ g, const float* __restrict__ beta,
    void* __restrict__ outp, int relu_mode)
{
    const int row = blockIdx.x * 4 + threadIdx.y;
    const int lane = threadIdx.x;
    const long long base = (long long)row * D_;
    float v0, v1;
    if (XBF) {
        v0 = __bfloat162float(((const bf16*)xin)[base + lane]);
        v1 = __bfloat162float(((const bf16*)xin)[base + lane + 64]);
    } else {
        v0 = ((const float*)xin)[base + lane];
        v1 = ((const float*)xin)[base + lane + 64];
    }
    if (addend) {
        v0 += __bfloat162float(addend[base + lane]);
        v1 += __bfloat162float(addend[base + lane + 64]);
    }
    if (relu_mode) { v0 = fmaxf(v0, 0.f); v1 = fmaxf(v1, 0.f); }
    float s = v0 + v1;
#pragma unroll
    for (int off = 32; off; off >>= 1) s += __shfl_xor(s, off);
    const float mean = s * (1.f / 128.f);
    const float c0 = v0 - mean, c1 = v1 - mean;
    float vs = c0 * c0 + c1 * c1;
#pragma unroll
    for (int off = 32; off; off >>= 1) vs += __shfl_xor(vs, off);
    const float rstd = rsqrtf(vs * (1.f / 128.f) + 1e-5f);
    const float r0 = c0 * rstd * g[lane] + beta[lane];
    const float r1 = c1 * rstd * g[lane + 64] + beta[lane + 64];
    if (OBF) {
        ((bf16*)outp)[base + lane]      = __float2bfloat16(r0);
        ((bf16*)outp)[base + lane + 64] = __float2bfloat16(r1);
    } else {
        ((float*)outp)[base + lane]      = r0;
        ((float*)outp)[base + lane + 64] = r1;
    }
}

// ---------------- driver ----------------
extern "C" void kernel_launch(void* const* d_in, const int* in_sizes, int n_in,
                              void* d_out, int out_size, void* d_ws, size_t ws_size,
                              hipStream_t stream)
{
    (void)in_sizes; (void)n_in; (void)out_size;

    const float* x_in    = (const float*)d_in[0];
    const float* mem     = (const float*)d_in[1];
    const float* data    = (const float*)d_in[2];
    const float* support = (const float*)d_in[3];
    const float* Wq  = (const float*)d_in[4];
    const float* bq  = (const float*)d_in[5];
    const float* Wk  = (const float*)d_in[6];
    const float* bk  = (const float*)d_in[7];
    const float* Wv  = (const float*)d_in[8];
    const float* bv  = (const float*)d_in[9];
    const float* Wo  = (const float*)d_in[10];
    const float* bo  = (const float*)d_in[11];
    const float* W1  = (const float*)d_in[12];
    const float* b1  = (const float*)d_in[13];
    const float* W2  = (const float*)d_in[14];
    const float* b2  = (const float*)d_in[15];
    const float* W3  = (const float*)d_in[16];
    const float* b3  = (const float*)d_in[17];
    const float* lng = (const float*)d_in[18];
    const float* lnb = (const float*)d_in[19];
    const float* gcnW= (const float*)d_in[20];
    const float* gcnb= (const float*)d_in[21];
    const float* skW = (const float*)d_in[22];
    const float* skb = (const float*)d_in[23];
    const float* outg= (const float*)d_in[24];
    const float* outb= (const float*)d_in[25];

    float* ws = (float*)d_ws;
    bf16*  Xb16 = (bf16*)ws;                    // [8][7800][128] bf16
    float* POOL = ws + 4000000LL;               // 14.8M floats transient
    bf16*  PB   = (bf16*)POOL;
    bf16*  WBF  = (bf16*)(ws + 18800000LL);
    float* BQKV = ws + 23275008LL;              // [6][384]
    float* BSK  = ws + 23277504LL;              // [24][128]
    float* KVB  = ws + 23280576LL;              // [8][8][16][16]
    float* KSB  = ws + 23296960LL;              // [8][8][16]
    bf16*  DTBP = (bf16*)(ws + 23300000LL);     // persistent [192][128][384] (gated)
    const bool useDTBP = ws_size >= (size_t)113000000;

    bf16* WQKVT = WBF + 0;          // [6][384][128]
    bf16* WOT   = WBF + 294912;     // [6][128][128]
    bf16* W1T   = WBF + 393216;     // [3][512][128]
    bf16* W2T   = WBF + 589824;     // [3][128][512]
    bf16* W3T   = WBF + 786432;     // [3][325][128]
    bf16* SKWT  = WBF + 911232;     // [3][128][128]
    bf16* SUPT  = WBF + 960384;     // [325][384]
    bf16* GSKT  = WBF + 1085184;    // [3][24][128][640]
    bf16* GSUM  = WBF + 6983424;    // [24][128][640]

    float* SKIP = (float*)d_out;
    const int BIG = 1 << 30;
    dim3 blk(32, 8);
    auto TG = [](int rb, int C, int z) { return dim3((rb + 31) / 32, (C + 31) / 32, z); };

    // ---------------- prepass: weights ----------------
    tconv<0><<<TG(128,128,6),blk,0,stream>>>(Wq, WQKVT,          128,128,128, 16384, 128,128, 49152);
    tconv<0><<<TG(128,128,6),blk,0,stream>>>(Wk, WQKVT + 16384,  128,128,128, 16384, 128,128, 49152);
    tconv<0><<<TG(128,128,6),blk,0,stream>>>(Wv, WQKVT + 32768,  128,128,128, 16384, 128,128, 49152);
    tconv<0><<<TG(128,128,6),blk,0,stream>>>(Wo, WOT,            128,128,128, 16384, 128,128, 16384);
    tconv<0><<<TG(128,512,3),blk,0,stream>>>(W1, W1T,            128,512,512, 65536, 128,128, 65536);
    tconv<0><<<TG(512,128,3),blk,0,stream>>>(W2, W2T,            512,128,128, 65536, 512,512, 65536);
    tconv<0><<<TG(128,325,3),blk,0,stream>>>(W3, W3T,            128,325,325, 41600, 128,128, 41600);
    tconv<0><<<TG(128,128,3),blk,0,stream>>>(skW, SKWT,          128,128,128, 16384, 128,128, 16384);
    tconv<0><<<TG(384,325,1),blk,0,stream>>>(support, SUPT,      325,325,325, 0,     384,384, 0);
    bf16* gcnWbf = PB;   // transient
    conv_k<<<4096,256,0,stream>>>(gcnW, gcnWbf, 5898240LL, 128, 128, 128);
    for (int i = 0; i < NL_; ++i)
        gemm64(stream, 1, SKWT + i*16384, gcnWbf + (long long)i*1966080, nullptr,
               GSKT + (long long)i*1966080,
               128, 640, 128, 0, 81920, 81920, 128, 128, 640, 24, BIG, 0, 0, EPI_NONE, 1);
    gsum_k<<<2048,256,0,stream>>>(GSKT, GSUM, 1966080LL);
    bsk_k<<<24,128,0,stream>>>(gcnb, skW, skb, BSK);
    cbias_k<<<6,384,0,stream>>>(bq, bk, bv, BQKV);
    hipMemsetAsync(SKIP, 0, (size_t)SZ * sizeof(float), stream);

    // ---------------- prepass: static channels -> Hs -> one K=384 skip GEMM ----
    for (int c = 0; c < 2; ++c) {
        const int b0 = c * 4;
        const float* datab = data + (long long)b0 * U_;
        bf16* Hs    = PB + 0;          // [96][325][384]
        bf16* DTB   = useDTBP ? (DTBP + (long long)c * 96 * 49152) : (PB + 12000000LL);
        bf16* s1_cm = PB + 16800000LL; // [96][128][384]
        conv_k<<<2048,256,0,stream>>>(datab, Hs, 96LL*41600, 128, 128, 384);
        tconv<0><<<TG(384,128,96),blk,0,stream>>>(datab, DTB, 325,128,128, 41600, 384,384, 49152);
        gemm64(stream, 1, DTB, SUPT, nullptr, s1_cm, 128,325,384,
               49152, 0, 49152, 384,384,384, 96, 1, 0, 0, EPI_NONE, 1, 0, 384);
        tconv<1><<<TG(128,325,96),blk,0,stream>>>(s1_cm, Hs + 128, 128,325,384, 49152, 128,384, 124800);
        gemm64(stream, 1, SUPT, s1_cm, nullptr, Hs + 256, 325,128,384,
               0, 49152, 124800, 384,384,384, 96, BIG, 0, 0, EPI_NONE, 1);
        gemm64(stream, 1, Hs, GSUM, BSK, SKIP + (long long)b0*U_,
               325,128,384, 124800, 81920, 41600, 384, 640, 128, 96, 24, 128, 1, EPI_NONE, 0);
    }

    // ---------------- layers ----------------
    for (int i = 0; i < NL_; ++i) {
        // ======== self attention (QKV multi-out; fused attn+Wo+LN) ========
        {
            const int wi = i * 2;
            bf16* Q  = PB + 0;
            bf16* KB = PB + 8000000LL;
            bf16* VB = PB + 16000000LL;
            float* PART = POOL + 12000000LL;
            MOut mo{};
            mo.d[0] = Q;  mo.ldc_[0] = 128; mo.flg[0] = EPI_ELU1;
            mo.d[1] = KB; mo.ldc_[1] = 128; mo.flg[1] = EPI_ELU1;
            mo.d[2] = VB; mo.ldc_[2] = 128; mo.flg[2] = EPI_NONE;
            gemm3_64(stream, (i == 0) ? 0 : 1, (i == 0) ? (const void*)x_in : (const void*)Xb16,
                     WQKVT + (long long)wi*49152, BQKV + wi*384, mo, ROWS, 384, 128, 128, 128);
            kv_part_bf16<<<dim3(16,H_,8),256,0,stream>>>(KB, VB, PART, T_SELF, 16);
            kv_reduce2<<<dim3(H_,8),256,0,stream>>>(PART, KVB, KSB, 0, 16);
            gemmLN(stream, (i == 0) ? 0 : 1, 0, 1,
                   Q, WOT + (long long)wi*16384, bo + wi*128, nullptr,
                   (i == 0) ? (const void*)x_in : (const void*)Xb16,
                   lng + (i*3)*128, lnb + (i*3)*128, Xb16, KVB, KSB, ROWS, 128, 128, 128);
        }

        // ======== cross attention (KV multi-out; fused attn+Wo+LN) ========
        {
            const int wi = i * 2 + 1;
            for (int c = 0; c < 2; ++c) {
                const int b0 = c * 4;
                bf16* KB = PB + 0;
                bf16* VB = PB + 8000000LL;
                float* PART = POOL + 12000000LL;
                MOut mo{};
                mo.d[0] = KB; mo.ldc_[0] = 128; mo.flg[0] = EPI_ELU1;
                mo.d[1] = VB; mo.ldc_[1] = 128; mo.flg[1] = EPI_NONE;
                gemm3_64(stream, 0, mem + (long long)b0 * T_CROSS * D_,
                         WQKVT + (long long)wi*49152 + 16384, BQKV + wi*384 + 128, mo,
                         4*T_CROSS, 256, 128, 128, 128);
                kv_part_bf16<<<dim3(31,H_,4),256,0,stream>>>(KB, VB, PART, T_CROSS, 31);
                kv_reduce2<<<dim3(H_,4),256,0,stream>>>(PART, KVB, KSB, b0, 31);
            }
            bf16* Q = PB + 0;
            gemm64(stream, 1, Xb16, WQKVT + (long long)wi*49152, BQKV + wi*384, Q,
                   ROWS, 128, 128, 0,0,0, 128,128,128, 1,1,0, 0, EPI_ELU1, 1);
            gemmLN(stream, 1, 0, 1,
                   Q, WOT + (long long)wi*16384, bo + wi*128, nullptr,
                   Xb16, lng + (i*3+1)*128, lnb + (i*3+1)*128, Xb16, KVB, KSB, ROWS, 128, 128, 128);
        }

        // ======== FFN (W2+LN fused) + adjacency + diffusion + skip (2 chunks) ========
        for (int c = 0; c < 2; ++c) {
            const int b0 = c * 4;
            bf16* Xb = Xb16 + (long long)b0 * U_;

            bf16* FFH   = PB + 0;           // [31200][512]
            bf16* Ybf   = PB + 16000000LL;  // [31200][128]
            bf16* AST   = PB + 0;           // [96][325][384] (over FFH, dead)
            bf16* DTB   = useDTBP ? (DTBP + (long long)c * 96 * 49152) : (PB + 12000000LL);
            bf16* Hd    = PB + 21600000LL;  // [96][325][256]
            bf16* a1_cm = PB + 16800000LL;  // [96][128][384]

            gemm64(stream, 1, Xb, W1T + (long long)i*65536, b1 + i*512, FFH,
                   4*T_SELF, 512, 128, 0,0,0, 128,128,512, 1,1,0, 0, EPI_GELU, 1);
            gemmLN(stream, 1, 1, 0,
                   FFH, W2T + (long long)i*65536, b2 + i*128, Ybf,
                   Xb, lng + (i*3+2)*128, lnb + (i*3+2)*128, Xb, nullptr, nullptr,
                   4*T_SELF, 512, 512, 512);
            gemm64(stream, 1, W3T + (long long)i*41600, Ybf, b3 + i*325, AST,
                   325, 325, 128, 0, 41600, 124800, 128, 128, 384, 96, BIG, 0, 0, EPI_NONE, 1, 1, 384);
            if (!useDTBP)
                tconv<0><<<TG(384,128,96),blk,0,stream>>>(data + (long long)b0*U_, DTB,
                      325,128,128, 41600, 384,384, 49152);
            gemm64(stream, 1, DTB, AST, nullptr, a1_cm, 128,325,384,
                   49152, 124800, 49152, 384,384,384, 96, BIG, 0, 0, EPI_NONE, 1, 0, 384);
            tconv<1><<<TG(128,325,96),blk,0,stream>>>(a1_cm, Hd, 128,325,384, 49152, 128,256, 83200);
            gemm64(stream, 1, AST, a1_cm, nullptr, Hd + 128, 325,128,384,
                   124800, 49152, 83200, 384,384,256, 96, BIG, 0, 0, EPI_NONE, 1);
            gemm64(stream, 1, Hd, GSKT + (long long)i*1966080 + 384, nullptr,
                   SKIP + (long long)b0*U_, 325,128,256,
                   83200, 81920, 41600, 256, 640, 128, 96, 24, 0, 1, EPI_NONE, 0);
        }
    }

    // out = LN(relu(skip)) in place
    addln_k<0,0><<<ROWS/4, dim3(64,4),0,stream>>>(SKIP, nullptr, outg, outb, SKIP, 1);
}

// Round 19
// 2110.006 us; speedup vs baseline: 1.0490x; 1.0490x over previous
//
#include <hip/hip_runtime.h>
#include <hip/hip_bf16.h>
#include <math.h>

// ---------------- problem constants ----------------
#define B_   8
#define L_   24
#define LP_  48
#define N_   325
#define D_   128
#define H_   8
#define NL_  3
#define DFF_ 512

typedef __attribute__((ext_vector_type(8))) short s16x8;
typedef __attribute__((ext_vector_type(4))) float f32x4;
typedef __hip_bfloat16 bf16;

static const int  ROWS    = B_ * L_ * N_;        // 62400
static const int  T_SELF  = L_ * N_;             // 7800
static const int  T_CROSS = LP_ * N_;            // 15600
static const long long U_ = (long long)T_SELF * D_;   // 998,400
static const long long SZ = (long long)B_ * U_;       // 7,987,200

enum { EPI_NONE = 0, EPI_ELU1 = 1, EPI_GELU = 2 };

struct MOut { void* d[3]; int ldc_[3]; int flg[3]; };   // flg = epi (bf16 out implied)

__device__ __forceinline__ float apply_epi(float v, int epi) {
    if (epi == EPI_ELU1) return (v > 0.f) ? (v + 1.f) : expf(v);
    if (epi == EPI_GELU) return 0.5f * v * (1.f + erff(v * 0.70710678118654752f));
    return v;
}

// Bijective XCD-chunked swizzle (m204)
__device__ __forceinline__ int xcd_swz(int bid, int nwg) {
    int q = nwg >> 3, r = nwg & 7;
    int xcd = bid & 7, lid = bid >> 3;
    return (xcd < r ? xcd * (q + 1) : r * (q + 1) + (xcd - r) * q) + lid;
}

// =====================================================================
// 64x64-tile MFMA GEMM (18.4KB LDS -> 8 blocks/CU). K % 64 == 0.
// 1D grid.x = MB*NB, decoded n-fast after XCD swizzle.
// =====================================================================
template<int ABF>
__global__ __launch_bounds__(256) void gk64(
    const void* __restrict__ Av, const bf16* __restrict__ Bt,
    const float* __restrict__ bias, void* __restrict__ Cv,
    int M, int Nc, int K,
    long long sA, long long sB, long long sC,
    int lda, int ldb, int ldc,
    int bmod, long long sBias, int accum, int epi, int obf, int rowbias, int npad)
{
    const int batch = blockIdx.z;
    const int NB = (npad + 63) >> 6;
    const int wgid = xcd_swz(blockIdx.x, gridDim.x);
    const int m0 = (wgid / NB) * 64, n0 = (wgid % NB) * 64;
    const int tid = threadIdx.x, lane = tid & 63;
    const int w = tid >> 6, wm = w >> 1, wn = w & 1;
    const int r16 = lane & 15, kb = lane >> 4;

    __shared__ __align__(16) bf16 shm[64 * 144];

    const float* Af = ABF ? nullptr : ((const float*)Av + (long long)batch * sA);
    const bf16*  Ab = ABF ? ((const bf16*)Av + (long long)batch * sA) : nullptr;
    const bf16*  Bp = Bt + (long long)(batch % bmod) * sB;

    f32x4 acc[2][2];
#pragma unroll
    for (int i = 0; i < 2; ++i)
#pragma unroll
        for (int j = 0; j < 2; ++j) acc[i][j] = f32x4{0.f, 0.f, 0.f, 0.f};

    for (int k0 = 0; k0 < K; k0 += 64) {
#pragma unroll
        for (int s = 0; s < 2; ++s) {
            int slot = tid + s * 256;
            int row = slot >> 3, kg = slot & 7;
            int m = m0 + row, k = k0 + kg * 8;
            union { s16x8 v; bf16 h[8]; } val;
            if (m < M) {
                if (ABF) {
                    val.v = *(const s16x8*)(Ab + (long long)m * lda + k);
                } else {
                    f32x4 v0 = *(const f32x4*)(Af + (long long)m * lda + k);
                    f32x4 v1 = *(const f32x4*)(Af + (long long)m * lda + k + 4);
#pragma unroll
                    for (int e = 0; e < 4; ++e) {
                        val.h[e]     = __float2bfloat16(v0[e]);
                        val.h[e + 4] = __float2bfloat16(v1[e]);
                    }
                }
            } else {
#pragma unroll
                for (int e = 0; e < 8; ++e) val.h[e] = __float2bfloat16(0.f);
            }
            *(s16x8*)&shm[row * 72 + kg * 8] = val.v;
        }
#pragma unroll
        for (int s = 0; s < 2; ++s) {
            int slot = tid + s * 256;
            int row = slot >> 3, kg = slot & 7;
            int n = n0 + row, k = k0 + kg * 8;
            union { s16x8 v; bf16 h[8]; } val;
            if (n < Nc) {
                val.v = *(const s16x8*)(Bp + (long long)n * ldb + k);
            } else {
#pragma unroll
                for (int e = 0; e < 8; ++e) val.h[e] = __float2bfloat16(0.f);
            }
            *(s16x8*)&shm[4608 + row * 72 + kg * 8] = val.v;
        }
        __syncthreads();
#pragma unroll
        for (int kh = 0; kh < 2; ++kh) {
            s16x8 av[2], bv[2];
#pragma unroll
            for (int mi = 0; mi < 2; ++mi)
                av[mi] = *(const s16x8*)&shm[(wm * 32 + mi * 16 + r16) * 72 + kh * 32 + kb * 8];
#pragma unroll
            for (int ni = 0; ni < 2; ++ni)
                bv[ni] = *(const s16x8*)&shm[4608 + (wn * 32 + ni * 16 + r16) * 72 + kh * 32 + kb * 8];
#pragma unroll
            for (int mi = 0; mi < 2; ++mi)
#pragma unroll
                for (int ni = 0; ni < 2; ++ni)
                    acc[mi][ni] = __builtin_amdgcn_mfma_f32_16x16x32_bf16(
                        av[mi], bv[ni], acc[mi][ni], 0, 0, 0);
        }
        __syncthreads();
    }

    const float* bp = bias ? (bias + (long long)(batch % bmod) * sBias) : nullptr;
    if (obf) {
        bf16* Cb = (bf16*)Cv + (long long)batch * sC;
#pragma unroll
        for (int mi = 0; mi < 2; ++mi)
#pragma unroll
            for (int ni = 0; ni < 2; ++ni)
#pragma unroll
                for (int rr = 0; rr < 4; ++rr) {
                    int row = wm * 32 + mi * 16 + kb * 4 + rr;
                    int col = wn * 32 + ni * 16 + r16;
                    int m = m0 + row, n = n0 + col;
                    float v = 0.f;
                    if (m < M && n < Nc) {
                        v = acc[mi][ni][rr];
                        if (bp) v += rowbias ? bp[m] : bp[n];
                        v = apply_epi(v, epi);
                    }
                    shm[row * 72 + col] = __float2bfloat16(v);
                }
        __syncthreads();
#pragma unroll
        for (int it = 0; it < 2; ++it) {
            int row = (tid >> 3) + it * 32;
            int col = (tid & 7) * 8;
            int m = m0 + row, nglob = n0 + col;
            if (m < M && nglob < npad)
                *(s16x8*)(Cb + (long long)m * ldc + nglob) = *(const s16x8*)&shm[row * 72 + col];
        }
        return;
    }

    float* Cf = (float*)Cv + (long long)batch * sC;
#pragma unroll
    for (int mi = 0; mi < 2; ++mi) {
#pragma unroll
        for (int ni = 0; ni < 2; ++ni) {
#pragma unroll
            for (int rr = 0; rr < 4; ++rr) {
                int m = m0 + wm * 32 + mi * 16 + kb * 4 + rr;
                int n = n0 + wn * 32 + ni * 16 + r16;
                if (m >= M || n >= Nc) continue;
                float v = acc[mi][ni][rr];
                if (bp) v += rowbias ? bp[m] : bp[n];
                v = apply_epi(v, epi);
                long long ci = (long long)m * ldc + n;
                if (accum) Cf[ci] += v; else Cf[ci] = v;
            }
        }
    }
}

// =====================================================================
// 64x64 MULTI GEMM (z==1, Nc = 128*NOUT), XCD-swizzled 1D grid.
// =====================================================================
template<int ABF>
__global__ __launch_bounds__(256) void gk64m(
    const void* __restrict__ Av, const bf16* __restrict__ Bt,
    const float* __restrict__ bias, MOut mo, int M, int K, int lda, int ldb, int NB)
{
    const int wgid = xcd_swz(blockIdx.x, gridDim.x);
    const int bn = wgid % NB;
    const int m0 = (wgid / NB) * 64, n0 = bn * 64;
    const int tid = threadIdx.x, lane = tid & 63;
    const int w = tid >> 6, wm = w >> 1, wn = w & 1;
    const int r16 = lane & 15, kb = lane >> 4;

    __shared__ __align__(16) bf16 shm[64 * 144];

    const float* Af = ABF ? nullptr : (const float*)Av;
    const bf16*  Ab = ABF ? (const bf16*)Av : nullptr;

    f32x4 acc[2][2];
#pragma unroll
    for (int i = 0; i < 2; ++i)
#pragma unroll
        for (int j = 0; j < 2; ++j) acc[i][j] = f32x4{0.f, 0.f, 0.f, 0.f};

    for (int k0 = 0; k0 < K; k0 += 64) {
#pragma unroll
        for (int s = 0; s < 2; ++s) {
            int slot = tid + s * 256;
            int row = slot >> 3, kg = slot & 7;
            int m = m0 + row, k = k0 + kg * 8;
            union { s16x8 v; bf16 h[8]; } val;
            if (m < M) {
                if (ABF) {
                    val.v = *(const s16x8*)(Ab + (long long)m * lda + k);
                } else {
                    f32x4 v0 = *(const f32x4*)(Af + (long long)m * lda + k);
                    f32x4 v1 = *(const f32x4*)(Af + (long long)m * lda + k + 4);
#pragma unroll
                    for (int e = 0; e < 4; ++e) {
                        val.h[e]     = __float2bfloat16(v0[e]);
                        val.h[e + 4] = __float2bfloat16(v1[e]);
                    }
                }
            } else {
#pragma unroll
                for (int e = 0; e < 8; ++e) val.h[e] = __float2bfloat16(0.f);
            }
            *(s16x8*)&shm[row * 72 + kg * 8] = val.v;
        }
#pragma unroll
        for (int s = 0; s < 2; ++s) {
            int slot = tid + s * 256;
            int row = slot >> 3, kg = slot & 7;
            int n = n0 + row, k = k0 + kg * 8;
            *(s16x8*)&shm[4608 + row * 72 + kg * 8] =
                *(const s16x8*)(Bt + (long long)n * ldb + k);
        }
        __syncthreads();
#pragma unroll
        for (int kh = 0; kh < 2; ++kh) {
            s16x8 av[2], bv[2];
#pragma unroll
            for (int mi = 0; mi < 2; ++mi)
                av[mi] = *(const s16x8*)&shm[(wm * 32 + mi * 16 + r16) * 72 + kh * 32 + kb * 8];
#pragma unroll
            for (int ni = 0; ni < 2; ++ni)
                bv[ni] = *(const s16x8*)&shm[4608 + (wn * 32 + ni * 16 + r16) * 72 + kh * 32 + kb * 8];
#pragma unroll
            for (int mi = 0; mi < 2; ++mi)
#pragma unroll
                for (int ni = 0; ni < 2; ++ni)
                    acc[mi][ni] = __builtin_amdgcn_mfma_f32_16x16x32_bf16(
                        av[mi], bv[ni], acc[mi][ni], 0, 0, 0);
        }
        __syncthreads();
    }

    const int oi = bn >> 1;
    const int epi_ = mo.flg[oi];
    bf16* Cb = (bf16*)mo.d[oi];
    const int ldcc = mo.ldc_[oi];
    const int cbase = (bn & 1) * 64;
#pragma unroll
    for (int mi = 0; mi < 2; ++mi)
#pragma unroll
        for (int ni = 0; ni < 2; ++ni)
#pragma unroll
            for (int rr = 0; rr < 4; ++rr) {
                int row = wm * 32 + mi * 16 + kb * 4 + rr;
                int col = wn * 32 + ni * 16 + r16;
                int m = m0 + row;
                float v = 0.f;
                if (m < M) {
                    v = acc[mi][ni][rr] + bias[n0 + col];
                    v = apply_epi(v, epi_);
                }
                shm[row * 72 + col] = __float2bfloat16(v);
            }
    __syncthreads();
#pragma unroll
    for (int it = 0; it < 2; ++it) {
        int row = (tid >> 3) + it * 32;
        int col = (tid & 7) * 8;
        int m = m0 + row;
        if (m < M)
            *(s16x8*)(Cb + (long long)m * ldcc + cbase + col) = *(const s16x8*)&shm[row * 72 + col];
    }
}

// =====================================================================
// gkLN: 64x128 full-row GEMM + fused residual+LayerNorm epilogue.
// ATTN: A-operand is raw elu'd Q-projection; the linear-attention combine
//   is computed during A staging with vectorized f32x4 kv/ksum loads.
// WRAW: also store raw (A@Bt + bias) to rawC. RBF: resid dtype.
// =====================================================================
template<int RBF, int WRAW, int ATTN>
__global__ __launch_bounds__(256) void gkLN(
    const bf16* __restrict__ Ab, const bf16* __restrict__ Bt,
    const float* __restrict__ bias, bf16* __restrict__ rawC,
    const void* __restrict__ resid, const float* __restrict__ g,
    const float* __restrict__ beta, bf16* __restrict__ outp,
    const float* __restrict__ kvt, const float* __restrict__ kst,
    int M, int K, int lda, int ldb)
{
    const int m0 = blockIdx.x * 64;
    const int tid = threadIdx.x, lane = tid & 63;
    const int w = tid >> 6, wm = w >> 1, wn = w & 1;
    const int r16 = lane & 15, kb = lane >> 4;

    __shared__ __align__(16) bf16 shm[64 * 72 + 128 * 72];  // A | B; epi reuse [64][136]
    __shared__ float red[2][2][64];

    f32x4 acc[2][4];
#pragma unroll
    for (int i = 0; i < 2; ++i)
#pragma unroll
        for (int j = 0; j < 4; ++j) acc[i][j] = f32x4{0.f, 0.f, 0.f, 0.f};

    for (int k0 = 0; k0 < K; k0 += 64) {
#pragma unroll
        for (int s = 0; s < 2; ++s) {                  // A[64][64]
            int slot = tid + s * 256;
            int row = slot >> 3, kg = slot & 7;
            int m = m0 + row, k = k0 + kg * 8;
            union { s16x8 v; bf16 h[8]; } val;
            if (m < M) {
                if (ATTN) {
                    const int h = k >> 4, d0 = k & 8;
                    const int b = m / T_SELF;
                    const bf16* qrow = Ab + (long long)m * 128 + h * 16;
                    const float* ksp = kst + ((b << 3) + h) * 16;
                    const float* kvp = kvt + ((long long)((b << 3) + h) << 8) + d0;
                    union { s16x8 v; bf16 h8[8]; } q0, q1;
                    q0.v = *(const s16x8*)(qrow);
                    q1.v = *(const s16x8*)(qrow + 8);
                    float q[16];
#pragma unroll
                    for (int e = 0; e < 8; ++e) {
                        q[e]     = __bfloat162float(q0.h8[e]);
                        q[e + 8] = __bfloat162float(q1.h8[e]);
                    }
                    float den = 1e-6f;
#pragma unroll
                    for (int e4 = 0; e4 < 4; ++e4) {
                        f32x4 ks4 = *(const f32x4*)(ksp + e4 * 4);
#pragma unroll
                        for (int t = 0; t < 4; ++t)
                            den = fmaf(q[e4 * 4 + t], ks4[t], den);
                    }
                    const float rd = 1.f / den;
                    float o[8];
#pragma unroll
                    for (int j = 0; j < 8; ++j) o[j] = 0.f;
#pragma unroll
                    for (int e = 0; e < 16; ++e) {
                        f32x4 a = *(const f32x4*)(kvp + e * 16);
                        f32x4 bb = *(const f32x4*)(kvp + e * 16 + 4);
#pragma unroll
                        for (int t = 0; t < 4; ++t) {
                            o[t]     = fmaf(q[e], a[t],  o[t]);
                            o[t + 4] = fmaf(q[e], bb[t], o[t + 4]);
                        }
                    }
#pragma unroll
                    for (int j = 0; j < 8; ++j)
                        val.h[j] = __float2bfloat16(o[j] * rd);
                } else {
                    val.v = *(const s16x8*)(Ab + (long long)m * lda + k);
                }
            } else {
#pragma unroll
                for (int e = 0; e < 8; ++e) val.h[e] = __float2bfloat16(0.f);
            }
            *(s16x8*)&shm[row * 72 + kg * 8] = val.v;
        }
#pragma unroll
        for (int s = 0; s < 4; ++s) {                  // B[128][64]
            int slot = tid + s * 256;
            int row = slot >> 3, kg = slot & 7;
            *(s16x8*)&shm[4608 + row * 72 + kg * 8] =
                *(const s16x8*)(Bt + (long long)row * ldb + k0 + kg * 8);
        }
        __syncthreads();
#pragma unroll
        for (int kh = 0; kh < 2; ++kh) {
            s16x8 av[2], bv[4];
#pragma unroll
            for (int mi = 0; mi < 2; ++mi)
                av[mi] = *(const s16x8*)&shm[(wm * 32 + mi * 16 + r16) * 72 + kh * 32 + kb * 8];
#pragma unroll
            for (int ni = 0; ni < 4; ++ni)
                bv[ni] = *(const s16x8*)&shm[4608 + (wn * 64 + ni * 16 + r16) * 72 + kh * 32 + kb * 8];
#pragma unroll
            for (int mi = 0; mi < 2; ++mi)
#pragma unroll
                for (int ni = 0; ni < 4; ++ni)
                    acc[mi][ni] = __builtin_amdgcn_mfma_f32_16x16x32_bf16(
                        av[mi], bv[ni], acc[mi][ni], 0, 0, 0);
        }
        __syncthreads();
    }

    // ---- epilogue: v = acc + bias; (raw write); t = v + resid; LN ----
    float psum[8], psq[8];
#pragma unroll
    for (int t = 0; t < 8; ++t) { psum[t] = 0.f; psq[t] = 0.f; }

#pragma unroll
    for (int mi = 0; mi < 2; ++mi)
#pragma unroll
        for (int rr = 0; rr < 4; ++rr) {
            const int row = wm * 32 + mi * 16 + kb * 4 + rr;
            const int m = m0 + row;
#pragma unroll
            for (int ni = 0; ni < 4; ++ni) {
                const int col = wn * 64 + ni * 16 + r16;
                float v = acc[mi][ni][rr] + bias[col];
                if (WRAW) shm[row * 136 + col] = __float2bfloat16(v);
                float r = 0.f;
                if (m < M)
                    r = RBF ? __bfloat162float(((const bf16*)resid)[(long long)m * 128 + col])
                            : ((const float*)resid)[(long long)m * 128 + col];
                float t = v + r;
                acc[mi][ni][rr] = t;
                psum[mi * 4 + rr] += t;
                psq[mi * 4 + rr]  += t * t;
            }
        }

    if (WRAW) {
        __syncthreads();
#pragma unroll
        for (int it = 0; it < 4; ++it) {
            int id = tid + it * 256;
            int row = id >> 4, colc = (id & 15) * 8;
            int m = m0 + row;
            if (m < M)
                *(s16x8*)(rawC + (long long)m * 128 + colc) = *(const s16x8*)&shm[row * 136 + colc];
        }
    }

#pragma unroll
    for (int off = 1; off < 16; off <<= 1) {
#pragma unroll
        for (int t = 0; t < 8; ++t) {
            psum[t] += __shfl_xor(psum[t], off);
            psq[t]  += __shfl_xor(psq[t], off);
        }
    }
    __syncthreads();
    if (r16 == 0) {
#pragma unroll
        for (int mi = 0; mi < 2; ++mi)
#pragma unroll
            for (int rr = 0; rr < 4; ++rr) {
                const int row = wm * 32 + mi * 16 + kb * 4 + rr;
                red[wn][0][row] = psum[mi * 4 + rr];
                red[wn][1][row] = psq[mi * 4 + rr];
            }
    }
    __syncthreads();

#pragma unroll
    for (int mi = 0; mi < 2; ++mi)
#pragma unroll
        for (int rr = 0; rr < 4; ++rr) {
            const int row = wm * 32 + mi * 16 + kb * 4 + rr;
            const float mean = (red[0][0][row] + red[1][0][row]) * (1.f / 128.f);
            const float msq  = (red[0][1][row] + red[1][1][row]) * (1.f / 128.f);
            const float rstd = rsqrtf(msq - mean * mean + 1e-5f);
#pragma unroll
            for (int ni = 0; ni < 4; ++ni) {
                const int col = wn * 64 + ni * 16 + r16;
                shm[row * 136 + col] = __float2bfloat16(
                    (acc[mi][ni][rr] - mean) * rstd * g[col] + beta[col]);
            }
        }
    __syncthreads();
#pragma unroll
    for (int it = 0; it < 4; ++it) {
        int id = tid + it * 256;
        int row = id >> 4, colc = (id & 15) * 8;
        int m = m0 + row;
        if (m < M)
            *(s16x8*)(outp + (long long)m * 128 + colc) = *(const s16x8*)&shm[row * 136 + colc];
    }
}

static inline void gemm64(hipStream_t st, int abf, const void* A, const bf16* Bt,
                          const float* bias, void* C,
                          int M, int Nc, int K,
                          long long sA, long long sB, long long sC,
                          int lda, int ldb, int ldc,
                          int z, int bmod, long long sBias, int accum, int epi, int obf,
                          int rowbias = 0, int npad = 0)
{
    if (npad < Nc) npad = Nc;
    dim3 g(((npad + 63) / 64) * ((M + 63) / 64), 1, z);
    if (abf) gk64<1><<<g,256,0,st>>>(A,Bt,bias,C,M,Nc,K,sA,sB,sC,lda,ldb,ldc,bmod,sBias,accum,epi,obf,rowbias,npad);
    else     gk64<0><<<g,256,0,st>>>(A,Bt,bias,C,M,Nc,K,sA,sB,sC,lda,ldb,ldc,bmod,sBias,accum,epi,obf,rowbias,npad);
}

static inline void gemm3_64(hipStream_t st, int abf, const void* A, const bf16* Bt,
                            const float* bias, const MOut& mo, int M, int Nc, int K,
                            int lda, int ldb)
{
    const int NB = Nc / 64;
    dim3 g(NB * ((M + 63) / 64), 1, 1);
    if (abf) gk64m<1><<<g,256,0,st>>>(A,Bt,bias,mo,M,K,lda,ldb,NB);
    else     gk64m<0><<<g,256,0,st>>>(A,Bt,bias,mo,M,K,lda,ldb,NB);
}

static inline void gemmLN(hipStream_t st, int rbf, int wraw, int attn,
                          const bf16* A, const bf16* Bt, const float* bias, bf16* rawC,
                          const void* resid, const float* g, const float* beta, bf16* outp,
                          const float* kvt, const float* kst,
                          int M, int K, int lda, int ldb)
{
    dim3 gr((M + 63) / 64);
    if (attn) {
        if (rbf) gkLN<1,0,1><<<gr,256,0,st>>>(A,Bt,bias,rawC,resid,g,beta,outp,kvt,kst,M,K,lda,ldb);
        else     gkLN<0,0,1><<<gr,256,0,st>>>(A,Bt,bias,rawC,resid,g,beta,outp,kvt,kst,M,K,lda,ldb);
    } else if (rbf) {
        if (wraw) gkLN<1,1,0><<<gr,256,0,st>>>(A,Bt,bias,rawC,resid,g,beta,outp,kvt,kst,M,K,lda,ldb);
        else      gkLN<1,0,0><<<gr,256,0,st>>>(A,Bt,bias,rawC,resid,g,beta,outp,kvt,kst,M,K,lda,ldb);
    } else {
        if (wraw) gkLN<0,1,0><<<gr,256,0,st>>>(A,Bt,bias,rawC,resid,g,beta,outp,kvt,kst,M,K,lda,ldb);
        else      gkLN<0,0,0><<<gr,256,0,st>>>(A,Bt,bias,rawC,resid,g,beta,outp,kvt,kst,M,K,lda,ldb);
    }
}

// =====================================================================
// transpose-convert
// =====================================================================
template<int SBF>
__global__ __launch_bounds__(256) void tconv(
    const void* __restrict__ srcv, bf16* __restrict__ dst,
    int R, int C, int lds_, long long sS, int rbound, int drs, long long sD)
{
    const int bz = blockIdx.z;
    const float* sf = SBF ? nullptr : ((const float*)srcv + (long long)bz * sS);
    const bf16* sb = SBF ? ((const bf16*)srcv + (long long)bz * sS) : nullptr;
    bf16* dp = dst + (long long)bz * sD;
    __shared__ float t[32][33];
    const int r0 = blockIdx.x * 32, c0 = blockIdx.y * 32;
    for (int i = threadIdx.y; i < 32; i += 8) {
        int r = r0 + i, c = c0 + threadIdx.x;
        float v = 0.f;
        if (r < R && c < C)
            v = SBF ? __bfloat162float(sb[(long long)r * lds_ + c]) : sf[(long long)r * lds_ + c];
        t[i][threadIdx.x] = v;
    }
    __syncthreads();
    for (int i = threadIdx.y; i < 32; i += 8) {
        int c = c0 + i, r = r0 + threadIdx.x;
        if (c < C && r < rbound) dp[(long long)c * drs + r] = __float2bfloat16(t[threadIdx.x][i]);
    }
}

// strided f32 -> bf16 convert
__global__ __launch_bounds__(256) void conv_k(
    const float* __restrict__ src, bf16* __restrict__ dst,
    long long total, int C, int slds, int dldd)
{
    for (long long idx = blockIdx.x * 256LL + threadIdx.x; idx < total;
         idx += (long long)gridDim.x * 256) {
        long long r = idx / C; int c = (int)(idx - r * C);
        dst[r * dldd + c] = __float2bfloat16(src[r * slds + c]);
    }
}

// GSUM[j] = sum_i GSKT[i][j]
__global__ __launch_bounds__(256) void gsum_k(
    const bf16* __restrict__ gskt, bf16* __restrict__ gsum, long long per)
{
    for (long long j = blockIdx.x * 256LL + threadIdx.x; j < per;
         j += (long long)gridDim.x * 256) {
        float a = __bfloat162float(gskt[j]) + __bfloat162float(gskt[per + j])
                + __bfloat162float(gskt[2 * per + j]);
        gsum[j] = __float2bfloat16(a);
    }
}

// BSK[l][o] = sum_i ( skb[i][o] + sum_c gcnb[i*24+l][c] * skW[i][c][o] )
__global__ __launch_bounds__(128) void bsk_k(
    const float* __restrict__ gcnb, const float* __restrict__ skW,
    const float* __restrict__ skb, float* __restrict__ out)
{
    const int l = blockIdx.x, o = threadIdx.x;
    float acc = 0.f;
    for (int i = 0; i < NL_; ++i) {
        acc += skb[i * 128 + o];
        const float* gb = gcnb + (i * 24 + l) * 128;
        const float* sw = skW + i * 16384;
        for (int c = 0; c < 128; ++c) acc += gb[c] * sw[c * 128 + o];
    }
    out[l * 128 + o] = acc;
}

__global__ __launch_bounds__(384) void cbias_k(
    const float* __restrict__ bq, const float* __restrict__ bk,
    const float* __restrict__ bv, float* __restrict__ bqkv)
{
    const int wi = blockIdx.x, j = threadIdx.x;
    float v = (j < 128) ? bq[wi * 128 + j] : (j < 256) ? bk[wi * 128 + j - 128] : bv[wi * 128 + j - 256];
    bqkv[wi * 384 + j] = v;
}

// ---------------- linear attention partial kv ----------------
__global__ __launch_bounds__(256) void kv_part_bf16(
    const bf16* __restrict__ kp, const bf16* __restrict__ vp,
    float* __restrict__ part, int T, int TC)
{
    const int z = blockIdx.z, h = blockIdx.y, tc = blockIdx.x;
    kp += (long long)z * T * D_;
    vp += (long long)z * T * D_;
    const int t0 = tc * 512;
    const int tend = min(T, t0 + 512);
    const int tid = threadIdx.x;
    const int e = tid >> 4, d = tid & 15;
    __shared__ float sk[64][16];
    __shared__ float sv[64][16];
    float acc = 0.f, asum = 0.f;
    for (int tb = t0; tb < tend; tb += 64) {
#pragma unroll
        for (int r = 0; r < 4; ++r) {
            int idx = tid + r * 256, tt = idx >> 4, c = idx & 15;
            int t = tb + tt;
            float kk = 0.f, vv = 0.f;
            if (t < tend) {
                long long gi = (long long)t * D_ + h * 16 + c;
                kk = __bfloat162float(kp[gi]);
                vv = __bfloat162float(vp[gi]);
            }
            sk[tt][c] = kk; sv[tt][c] = vv;
        }
        __syncthreads();
#pragma unroll 8
        for (int tt = 0; tt < 64; ++tt) {
            float ke = sk[tt][e];
            acc  = fmaf(ke, sv[tt][d], acc);
            asum += ke;
        }
        __syncthreads();
    }
    float* pp = part + (((long long)z * TC + tc) * H_ + h) * 272;
    pp[e * 16 + d] = acc;
    if (d == 0) pp[256 + e] = asum;
}

__global__ __launch_bounds__(256) void kv_reduce2(
    const float* __restrict__ part, float* __restrict__ kv,
    float* __restrict__ ksum, int b0, int TC)
{
    const int h = blockIdx.x, z = blockIdx.y, b = b0 + z;
    const float* pz = part + (long long)z * TC * H_ * 272;
    const int tid = threadIdx.x, e = tid >> 4, d = tid & 15;
    float acc = 0.f;
    for (int tc = 0; tc < TC; ++tc) acc += pz[((long long)tc * H_ + h) * 272 + e * 16 + d];
    kv[((long long)(b * H_ + h) * 16 + e) * 16 + d] = acc;
    if (d == 0) {
        float s = 0.f;
        for (int tc = 0; tc < TC; ++tc) s += pz[((long long)tc * H_ + h) * 272 + 256 + e];
        ksum[(b * H_ + h) * 16 + e] = s;
    }
}

// ---------------- fused (residual|relu) + LayerNorm (final only) ----------------
template<int XBF, int OBF>
__global__ __launch_bounds__(256) void addln_k(
    const void* __restrict__ xin, const bf16* __restrict__ addend,
    const float* __restrict__ g, const float* __restrict__ beta,
    void* __restrict__ outp, int relu_mode)
{
    const int row = blockIdx.x * 4 + threadIdx.y;
    const int lane = threadIdx.x;
    const long long base = (long long)row * D_;
    float v0, v1;
    if (XBF) {
        v0 = __bfloat162float(((const bf16*)xin)[base + lane]);
        v1 = __bfloat162float(((const bf16*)xin)[base + lane + 64]);
    } else {
        v0 = ((const float*)xin)[base + lane];
        v1 = ((const float*)xin)[base + lane + 64];
    }
    if (addend) {
        v0 += __bfloat162float(addend[base + lane]);
        v1 += __bfloat162float(addend[base + lane + 64]);
    }
    if (relu_mode) { v0 = fmaxf(v0, 0.f); v1 = fmaxf(v1, 0.f); }
    float s = v0 + v1;
#pragma unroll
    for (int off = 32; off; off >>= 1) s += __shfl_xor(s, off);
    const float mean = s * (1.f / 128.f);
    const float c0 = v0 - mean, c1 = v1 - mean;
    float vs = c0 * c0 + c1 * c1;
#pragma unroll
    for (int off = 32; off; off >>= 1) vs += __shfl_xor(vs, off);
    const float rstd = rsqrtf(vs * (1.f / 128.f) + 1e-5f);
    const float r0 = c0 * rstd * g[lane] + beta[lane];
    const float r1 = c1 * rstd * g[lane + 64] + beta[lane + 64];
    if (OBF) {
        ((bf16*)outp)[base + lane]      = __float2bfloat16(r0);
        ((bf16*)outp)[base + lane + 64] = __float2bfloat16(r1);
    } else {
        ((float*)outp)[base + lane]      = r0;
        ((float*)outp)[base + lane + 64] = r1;
    }
}

// ---------------- driver ----------------
extern "C" void kernel_launch(void* const* d_in, const int* in_sizes, int n_in,
                              void* d_out, int out_size, void* d_ws, size_t ws_size,
                              hipStream_t stream)
{
    (void)in_sizes; (void)n_in; (void)out_size;

    const float* x_in    = (const float*)d_in[0];
    const float* mem     = (const float*)d_in[1];
    const float* data    = (const float*)d_in[2];
    const float* support = (const float*)d_in[3];
    const float* Wq  = (const float*)d_in[4];
    const float* bq  = (const float*)d_in[5];
    const float* Wk  = (const float*)d_in[6];
    const float* bk  = (const float*)d_in[7];
    const float* Wv  = (const float*)d_in[8];
    const float* bv  = (const float*)d_in[9];
    const float* Wo  = (const float*)d_in[10];
    const float* bo  = (const float*)d_in[11];
    const float* W1  = (const float*)d_in[12];
    const float* b1  = (const float*)d_in[13];
    const float* W2  = (const float*)d_in[14];
    const float* b2  = (const float*)d_in[15];
    const float* W3  = (const float*)d_in[16];
    const float* b3  = (const float*)d_in[17];
    const float* lng = (const float*)d_in[18];
    const float* lnb = (const float*)d_in[19];
    const float* gcnW= (const float*)d_in[20];
    const float* gcnb= (const float*)d_in[21];
    const float* skW = (const float*)d_in[22];
    const float* skb = (const float*)d_in[23];
    const float* outg= (const float*)d_in[24];
    const float* outb= (const float*)d_in[25];

    float* ws = (float*)d_ws;
    bf16*  Xb16 = (bf16*)ws;                    // [8][7800][128] bf16
    float* POOL = ws + 4000000LL;               // 14.8M floats transient
    bf16*  PB   = (bf16*)POOL;
    bf16*  WBF  = (bf16*)(ws + 18800000LL);
    float* BQKV = ws + 23275008LL;              // [6][384]
    float* BSK  = ws + 23277504LL;              // [24][128]
    float* KVB  = ws + 23280576LL;              // [8][8][16][16]
    float* KSB  = ws + 23296960LL;              // [8][8][16]
    bf16*  DTBP = (bf16*)(ws + 23300000LL);     // persistent [192][128][384] (gated)
    const bool useDTBP = ws_size >= (size_t)113000000;

    bf16* WQKVT = WBF + 0;          // [6][384][128]
    bf16* WOT   = WBF + 294912;     // [6][128][128]
    bf16* W1T   = WBF + 393216;     // [3][512][128]
    bf16* W2T   = WBF + 589824;     // [3][128][512]
    bf16* W3T   = WBF + 786432;     // [3][325][128]
    bf16* SKWT  = WBF + 911232;     // [3][128][128]
    bf16* SUPT  = WBF + 960384;     // [325][384]
    bf16* GSKT  = WBF + 1085184;    // [3][24][128][640]
    bf16* GSUM  = WBF + 6983424;    // [24][128][640]

    float* SKIP = (float*)d_out;
    const int BIG = 1 << 30;
    dim3 blk(32, 8);
    auto TG = [](int rb, int C, int z) { return dim3((rb + 31) / 32, (C + 31) / 32, z); };

    // ---------------- prepass: weights ----------------
    tconv<0><<<TG(128,128,6),blk,0,stream>>>(Wq, WQKVT,          128,128,128, 16384, 128,128, 49152);
    tconv<0><<<TG(128,128,6),blk,0,stream>>>(Wk, WQKVT + 16384,  128,128,128, 16384, 128,128, 49152);
    tconv<0><<<TG(128,128,6),blk,0,stream>>>(Wv, WQKVT + 32768,  128,128,128, 16384, 128,128, 49152);
    tconv<0><<<TG(128,128,6),blk,0,stream>>>(Wo, WOT,            128,128,128, 16384, 128,128, 16384);
    tconv<0><<<TG(128,512,3),blk,0,stream>>>(W1, W1T,            128,512,512, 65536, 128,128, 65536);
    tconv<0><<<TG(512,128,3),blk,0,stream>>>(W2, W2T,            512,128,128, 65536, 512,512, 65536);
    tconv<0><<<TG(128,325,3),blk,0,stream>>>(W3, W3T,            128,325,325, 41600, 128,128, 41600);
    tconv<0><<<TG(128,128,3),blk,0,stream>>>(skW, SKWT,          128,128,128, 16384, 128,128, 16384);
    tconv<0><<<TG(384,325,1),blk,0,stream>>>(support, SUPT,      325,325,325, 0,     384,384, 0);
    bf16* gcnWbf = PB;   // transient
    conv_k<<<4096,256,0,stream>>>(gcnW, gcnWbf, 5898240LL, 128, 128, 128);
    for (int i = 0; i < NL_; ++i)
        gemm64(stream, 1, SKWT + i*16384, gcnWbf + (long long)i*1966080, nullptr,
               GSKT + (long long)i*1966080,
               128, 640, 128, 0, 81920, 81920, 128, 128, 640, 24, BIG, 0, 0, EPI_NONE, 1);
    gsum_k<<<2048,256,0,stream>>>(GSKT, GSUM, 1966080LL);
    bsk_k<<<24,128,0,stream>>>(gcnb, skW, skb, BSK);
    cbias_k<<<6,384,0,stream>>>(bq, bk, bv, BQKV);
    hipMemsetAsync(SKIP, 0, (size_t)SZ * sizeof(float), stream);

    // ---------------- prepass: static channels -> Hs -> one K=384 skip GEMM ----
    for (int c = 0; c < 2; ++c) {
        const int b0 = c * 4;
        const float* datab = data + (long long)b0 * U_;
        bf16* Hs    = PB + 0;          // [96][325][384]
        bf16* DTB   = useDTBP ? (DTBP + (long long)c * 96 * 49152) : (PB + 12000000LL);
        bf16* s1_cm = PB + 16800000LL; // [96][128][384]
        conv_k<<<2048,256,0,stream>>>(datab, Hs, 96LL*41600, 128, 128, 384);
        tconv<0><<<TG(384,128,96),blk,0,stream>>>(datab, DTB, 325,128,128, 41600, 384,384, 49152);
        gemm64(stream, 1, DTB, SUPT, nullptr, s1_cm, 128,325,384,
               49152, 0, 49152, 384,384,384, 96, 1, 0, 0, EPI_NONE, 1, 0, 384);
        tconv<1><<<TG(128,325,96),blk,0,stream>>>(s1_cm, Hs + 128, 128,325,384, 49152, 128,384, 124800);
        gemm64(stream, 1, SUPT, s1_cm, nullptr, Hs + 256, 325,128,384,
               0, 49152, 124800, 384,384,384, 96, BIG, 0, 0, EPI_NONE, 1);
        gemm64(stream, 1, Hs, GSUM, BSK, SKIP + (long long)b0*U_,
               325,128,384, 124800, 81920, 41600, 384, 640, 128, 96, 24, 128, 1, EPI_NONE, 0);
    }

    // ---------------- layers ----------------
    for (int i = 0; i < NL_; ++i) {
        // ======== self attention (QKV multi-out; fused attn+Wo+LN) ========
        {
            const int wi = i * 2;
            bf16* Q  = PB + 0;
            bf16* KB = PB + 8000000LL;
            bf16* VB = PB + 16000000LL;
            float* PART = POOL + 12000000LL;
            MOut mo{};
            mo.d[0] = Q;  mo.ldc_[0] = 128; mo.flg[0] = EPI_ELU1;
            mo.d[1] = KB; mo.ldc_[1] = 128; mo.flg[1] = EPI_ELU1;
            mo.d[2] = VB; mo.ldc_[2] = 128; mo.flg[2] = EPI_NONE;
            gemm3_64(stream, (i == 0) ? 0 : 1, (i == 0) ? (const void*)x_in : (const void*)Xb16,
                     WQKVT + (long long)wi*49152, BQKV + wi*384, mo, ROWS, 384, 128, 128, 128);
            kv_part_bf16<<<dim3(16,H_,8),256,0,stream>>>(KB, VB, PART, T_SELF, 16);
            kv_reduce2<<<dim3(H_,8),256,0,stream>>>(PART, KVB, KSB, 0, 16);
            gemmLN(stream, (i == 0) ? 0 : 1, 0, 1,
                   Q, WOT + (long long)wi*16384, bo + wi*128, nullptr,
                   (i == 0) ? (const void*)x_in : (const void*)Xb16,
                   lng + (i*3)*128, lnb + (i*3)*128, Xb16, KVB, KSB, ROWS, 128, 128, 128);
        }

        // ======== cross attention (KV multi-out; fused attn+Wo+LN) ========
        {
            const int wi = i * 2 + 1;
            for (int c = 0; c < 2; ++c) {
                const int b0 = c * 4;
                bf16* KB = PB + 0;
                bf16* VB = PB + 8000000LL;
                float* PART = POOL + 12000000LL;
                MOut mo{};
                mo.d[0] = KB; mo.ldc_[0] = 128; mo.flg[0] = EPI_ELU1;
                mo.d[1] = VB; mo.ldc_[1] = 128; mo.flg[1] = EPI_NONE;
                gemm3_64(stream, 0, mem + (long long)b0 * T_CROSS * D_,
                         WQKVT + (long long)wi*49152 + 16384, BQKV + wi*384 + 128, mo,
                         4*T_CROSS, 256, 128, 128, 128);
                kv_part_bf16<<<dim3(31,H_,4),256,0,stream>>>(KB, VB, PART, T_CROSS, 31);
                kv_reduce2<<<dim3(H_,4),256,0,stream>>>(PART, KVB, KSB, b0, 31);
            }
            bf16* Q = PB + 0;
            gemm64(stream, 1, Xb16, WQKVT + (long long)wi*49152, BQKV + wi*384, Q,
                   ROWS, 128, 128, 0,0,0, 128,128,128, 1,1,0, 0, EPI_ELU1, 1);
            gemmLN(stream, 1, 0, 1,
                   Q, WOT + (long long)wi*16384, bo + wi*128, nullptr,
                   Xb16, lng + (i*3+1)*128, lnb + (i*3+1)*128, Xb16, KVB, KSB, ROWS, 128, 128, 128);
        }

        // ======== FFN (W2+LN fused) + adjacency + diffusion + skip (2 chunks) ========
        for (int c = 0; c < 2; ++c) {
            const int b0 = c * 4;
            bf16* Xb = Xb16 + (long long)b0 * U_;

            bf16* FFH   = PB + 0;           // [31200][512]
            bf16* Ybf   = PB + 16000000LL;  // [31200][128]
            bf16* AST   = PB + 0;           // [96][325][384] (over FFH, dead)
            bf16* DTB   = useDTBP ? (DTBP + (long long)c * 96 * 49152) : (PB + 12000000LL);
            bf16* Hd    = PB + 21600000LL;  // [96][325][256]
            bf16* a1_cm = PB + 16800000LL;  // [96][128][384]

            gemm64(stream, 1, Xb, W1T + (long long)i*65536, b1 + i*512, FFH,
                   4*T_SELF, 512, 128, 0,0,0, 128,128,512, 1,1,0, 0, EPI_GELU, 1);
            gemmLN(stream, 1, 1, 0,
                   FFH, W2T + (long long)i*65536, b2 + i*128, Ybf,
                   Xb, lng + (i*3+2)*128, lnb + (i*3+2)*128, Xb, nullptr, nullptr,
                   4*T_SELF, 512, 512, 512);
            gemm64(stream, 1, W3T + (long long)i*41600, Ybf, b3 + i*325, AST,
                   325, 325, 128, 0, 41600, 124800, 128, 128, 384, 96, BIG, 0, 0, EPI_NONE, 1, 1, 384);
            if (!useDTBP)
                tconv<0><<<TG(384,128,96),blk,0,stream>>>(data + (long long)b0*U_, DTB,
                      325,128,128, 41600, 384,384, 49152);
            gemm64(stream, 1, DTB, AST, nullptr, a1_cm, 128,325,384,
                   49152, 124800, 49152, 384,384,384, 96, BIG, 0, 0, EPI_NONE, 1, 0, 384);
            tconv<1><<<TG(128,325,96),blk,0,stream>>>(a1_cm, Hd, 128,325,384, 49152, 128,256, 83200);
            gemm64(stream, 1, AST, a1_cm, nullptr, Hd + 128, 325,128,384,
                   124800, 49152, 83200, 384,384,256, 96, BIG, 0, 0, EPI_NONE, 1);
            gemm64(stream, 1, Hd, GSKT + (long long)i*1966080 + 384, nullptr,
                   SKIP + (long long)b0*U_, 325,128,256,
                   83200, 81920, 41600, 256, 640, 128, 96, 24, 0, 1, EPI_NONE, 0);
        }
    }

    // out = LN(relu(skip)) in place
    addln_k<0,0><<<ROWS/4, dim3(64,4),0,stream>>>(SKIP, nullptr, outg, outb, SKIP, 1);
}